// Round 6
// baseline (550.595 us; speedup 1.0000x reference)
//
#include <hip/hip_runtime.h>

// Problem constants (fixed by the reference)
#define NTOK 8192
#define BDIM 32
#define GRU  256
#define HAN  512
#define INNER 128
static constexpr float SCALE = 0.08838834764831845f; // 128^-0.5

// ---------------------------------------------------------------------------
// K1: M[e][j] = SCALE * sum_i Wk[i][e] * Wq[i][j]      (M: [512][256])
// grid = 512 blocks x 256 threads; block e, thread j. 33.5 MFLOP total.
// Block 0 / wave 0 also computes the mask-ABI flag (int32 words vs bool
// bytes): 64 leading uint words all <=1  <=> int32 mask.
// ---------------------------------------------------------------------------
__global__ __launch_bounds__(256) void make_m(const float* __restrict__ Wk,
                                              const float* __restrict__ Wq,
                                              const void* __restrict__ maskp,
                                              float* __restrict__ M,
                                              int* __restrict__ flag) {
    const int e = blockIdx.x;     // 0..511
    const int j = threadIdx.x;    // 0..255
    float acc = 0.0f;
#pragma unroll 8
    for (int i = 0; i < INNER; ++i)
        acc = fmaf(Wk[(size_t)i * HAN + e], Wq[(size_t)i * GRU + j], acc);
    M[(size_t)e * GRU + j] = SCALE * acc;

    if (e == 0 && j < 64) {
        const unsigned int* mi = (const unsigned int*)maskp;
        const int ok = __all((int)(mi[j] <= 1u)) ? 1 : 0;
        if (j == 0) *flag = ok;
    }
}

// ---------------------------------------------------------------------------
// K2 (fused): per block of 16 tokens:
//   Phase A: w[tok][j] = sum_e edges[tok][e] * M[e][j]  (scale folded in M)
//     Thread layout tg=t&7 (token pair), jg=t>>3 (j quad). Within a wave all
//     8 tg-groups share the same M[e][j0..j0+3] address -> one 128B L2
//     transaction per e per wave (M is 512KB, L2-resident). VALU-bound
//     ~4096 FMA/thread. Accumulation order over e = sequential 0..511,
//     identical to the previous standalone GEMM (bit-identical w).
//   Phase B: stream chg: sim[b,n] = dot(chg[b,n,:], w[n,:]), mask -> -1e9,
//     softmax over b, coalesced transposed write out[n,b].
// grid = 512 blocks x 512 threads (2 blocks/CU, 16 waves/CU).
// ---------------------------------------------------------------------------
__global__ __launch_bounds__(512) void cal_sim_fused(const float* __restrict__ chg,
                                                     const float* __restrict__ edges,
                                                     const void* __restrict__ maskp,
                                                     const float* __restrict__ M,
                                                     const int* __restrict__ flag,
                                                     float* __restrict__ out) {
    __shared__ float w_lds[16][GRU];   // 16 KB
    __shared__ float sim[BDIM][17];    // padded: conflict-free transposed read
    __shared__ float mrow[16], srow[16];

    const int t  = threadIdx.x;
    const int n0 = blockIdx.x * 16;

    // ======================= Phase A: w-compute =======================
    {
        const int tg = t & 7;          // token-pair group: tokens tg*2, tg*2+1
        const int jg = t >> 3;         // 0..63 -> j0 = jg*4
        const int j0 = jg * 4;
        const int na = tg * 2;
        const int nb = na + 1;

        const float* ea_p = edges + (size_t)(n0 + na) * HAN;
        const float* eb_p = edges + (size_t)(n0 + nb) * HAN;

        float acc0[4] = {0.f, 0.f, 0.f, 0.f};
        float acc1[4] = {0.f, 0.f, 0.f, 0.f};

        for (int ec = 0; ec < HAN; ec += 16) {
            // edges fragments for this chunk (wave-merged redundant loads, L2)
            float4 ea[4], eb[4];
#pragma unroll
            for (int q = 0; q < 4; ++q) {
                ea[q] = *(const float4*)(ea_p + ec + q * 4);
                eb[q] = *(const float4*)(eb_p + ec + q * 4);
            }
#pragma unroll
            for (int q = 0; q < 4; ++q) {
                const float eav[4] = {ea[q].x, ea[q].y, ea[q].z, ea[q].w};
                const float ebv[4] = {eb[q].x, eb[q].y, eb[q].z, eb[q].w};
#pragma unroll
                for (int el = 0; el < 4; ++el) {
                    // 8-way wave-shared M load: 128B contiguous per wave
                    const float4 m4 =
                        *(const float4*)(M + (size_t)(ec + q * 4 + el) * GRU + j0);
                    const float va = eav[el];
                    const float vb = ebv[el];
                    acc0[0] = fmaf(va, m4.x, acc0[0]);
                    acc0[1] = fmaf(va, m4.y, acc0[1]);
                    acc0[2] = fmaf(va, m4.z, acc0[2]);
                    acc0[3] = fmaf(va, m4.w, acc0[3]);
                    acc1[0] = fmaf(vb, m4.x, acc1[0]);
                    acc1[1] = fmaf(vb, m4.y, acc1[1]);
                    acc1[2] = fmaf(vb, m4.z, acc1[2]);
                    acc1[3] = fmaf(vb, m4.w, acc1[3]);
                }
            }
        }
        *(float4*)&w_lds[na][j0] = make_float4(acc0[0], acc0[1], acc0[2], acc0[3]);
        *(float4*)&w_lds[nb][j0] = make_float4(acc1[0], acc1[1], acc1[2], acc1[3]);
    }
    __syncthreads();

    // ======================= Phase B: stream + softmax =======================
    const int wave = t >> 6;        // 0..7
    const int half = (t >> 5) & 1;  // which of the wave's 2 tokens
    const int dq   = t & 31;        // 8-float slice of dim 256
    const int nloc = wave * 2 + half;
    const int n    = n0 + nloc;

    // this lane's 8 floats of w[n,:] from LDS
    const float4 wr0 = *(const float4*)&w_lds[nloc][dq * 8];
    const float4 wr1 = *(const float4*)&w_lds[nloc][dq * 8 + 4];

    const int misi = *flag;         // uniform
    const int* mi = (const int*)maskp;
    const unsigned char* mb = (const unsigned char*)maskp;

#pragma unroll 8
    for (int b = 0; b < BDIM; ++b) {
        const float* cp = chg + ((size_t)b * NTOK + n) * GRU + dq * 8;
        const float4 c0 = *(const float4*)(cp);
        const float4 c1 = *(const float4*)(cp + 4);
        float p;
        p = c0.x * wr0.x;
        p = fmaf(c0.y, wr0.y, p);
        p = fmaf(c0.z, wr0.z, p);
        p = fmaf(c0.w, wr0.w, p);
        p = fmaf(c1.x, wr1.x, p);
        p = fmaf(c1.y, wr1.y, p);
        p = fmaf(c1.z, wr1.z, p);
        p = fmaf(c1.w, wr1.w, p);
        // reduce across the 32 lanes of this token
        p += __shfl_xor(p, 1, 64);
        p += __shfl_xor(p, 2, 64);
        p += __shfl_xor(p, 4, 64);
        p += __shfl_xor(p, 8, 64);
        p += __shfl_xor(p, 16, 64);
        if (dq == 0) {
            const size_t mofs = (size_t)b * NTOK + n;
            const int mval = misi ? mi[mofs] : (int)mb[mofs];
            sim[b][nloc] = mval ? p : -1e9f;
        }
    }
    __syncthreads();

    // softmax over batch for each of the 16 tokens
    if (t < 16) {
        float m = sim[0][t];
        for (int b = 1; b < BDIM; ++b) m = fmaxf(m, sim[b][t]);
        float s = 0.0f;
        for (int b = 0; b < BDIM; ++b) s += __expf(sim[b][t] - m);
        mrow[t] = m;
        srow[t] = 1.0f / s;
    }
    __syncthreads();

    // write out[n, b]: 512 floats per block, fully coalesced (2KB contiguous)
    {
        const int b  = t & 31;
        const int nl = t >> 5;
        out[(size_t)n0 * BDIM + t] = __expf(sim[b][nl] - mrow[nl]) * srow[nl];
    }
}

extern "C" void kernel_launch(void* const* d_in, const int* in_sizes, int n_in,
                              void* d_out, int out_size, void* d_ws, size_t ws_size,
                              hipStream_t stream) {
    const float* chg   = (const float*)d_in[0];  // [32, 8192, 256]
    const float* edges = (const float*)d_in[1];  // [8192, 512]
    const void*  mask  = d_in[2];                // [32, 8192] bool/int
    const float* Wq    = (const float*)d_in[3];  // [128, 256]
    const float* Wk    = (const float*)d_in[4];  // [128, 512]
    float* out = (float*)d_out;                  // [8192, 32]

    float* Mws  = (float*)d_ws;                    // [512][256] = 512 KB
    int*   flag = (int*)(Mws + (size_t)HAN * GRU); // 4 B

    // K1: M = SCALE * Wk^T @ Wq  (+ mask ABI flag)
    make_m<<<HAN, 256, 0, stream>>>(Wk, Wq, mask, Mws, flag);

    // K2: fused w-compute + sim + mask + softmax(batch) + transposed write
    cal_sim_fused<<<NTOK / 16, 512, 0, stream>>>(chg, edges, mask, Mws, flag, out);
}